// Round 6
// baseline (245.329 us; speedup 1.0000x reference)
//
#include <hip/hip_runtime.h>
#include <climits>

#define BATCH 128
#define IMG_H 512
#define IMG_W 512
#define BLOCKS_PER_BATCH 16
#define NTHREADS 256
#define ELEMS_PER_BLOCK (IMG_H * IMG_W / BLOCKS_PER_BATCH)   // 16384
#define VEC_PER_BLOCK   (ELEMS_PER_BLOCK / 4)                // 4096
#define NBLOCKS         (BATCH * BLOCKS_PER_BATCH)           // 2048

// Native vector type: __builtin_nontemporal_load requires a true clang
// vector (HIP's float4 is a class and is rejected).
typedef float f32x4 __attribute__((ext_vector_type(4)));

// ws layout (ints): ws[0] = arrival counter (zeroed by a memset node in
// kernel_launch); ws[64 + k*NBLOCKS + blk] = partial k of block blk,
// k = {0:count, 1:minh, 2:maxh, 3:minw, 4:maxw}. Partials need no init:
// every slot is written before the last block reads it.
__global__ __launch_bounds__(NTHREADS)
void rect_fused_kernel(const float* __restrict__ in, int* __restrict__ ws,
                       float* __restrict__ out) {
    const int blk   = blockIdx.x;
    const int batch = blk / BLOCKS_PER_BATCH;
    const int sub   = blk % BLOCKS_PER_BATCH;
    const int elemBase = sub * ELEMS_PER_BLOCK;
    int* const part = ws + 64;

    const f32x4* base =
        (const f32x4*)(in + (size_t)batch * IMG_H * IMG_W + elemBase);

    int count = 0;
    int minh = INT_MAX, maxh = -1;
    int minw = INT_MAX, maxw = -1;

    // 16 iterations; unroll 4 so 4 independent dwordx4 loads are in flight
    // before the first dependent VALU op (MLP for the HBM-bound stream).
    #pragma unroll 4
    for (int i = threadIdx.x; i < VEC_PER_BLOCK; i += NTHREADS) {
        f32x4 v = __builtin_nontemporal_load(&base[i]);  // read-once stream
        const int idx = elemBase + i * 4;      // element index within image
        const int h  = idx >> 9;               // /512
        const int w0 = idx & 511;              // %512 (float4 never crosses a row)

        const bool b0 = v.x > 0.5f;
        const bool b1 = v.y > 0.5f;
        const bool b2 = v.z > 0.5f;
        const bool b3 = v.w > 0.5f;
        count += (int)b0 + (int)b1 + (int)b2 + (int)b3;

        if (b0 | b1 | b2 | b3) {
            minh = min(minh, h);
            maxh = max(maxh, h);
            const int fw = b0 ? 0 : (b1 ? 1 : (b2 ? 2 : 3));
            const int lw = b3 ? 3 : (b2 ? 2 : (b1 ? 1 : 0));
            minw = min(minw, w0 + fw);
            maxw = max(maxw, w0 + lw);
        }
    }

    // wave (64-lane) butterfly reduction
    #pragma unroll
    for (int off = 32; off; off >>= 1) {
        count += __shfl_down(count, off);
        minh = min(minh, __shfl_down(minh, off));
        maxh = max(maxh, __shfl_down(maxh, off));
        minw = min(minw, __shfl_down(minw, off));
        maxw = max(maxw, __shfl_down(maxw, off));
    }

    __shared__ int sc[4], smh[4], sMh[4], smw[4], sMw[4];
    __shared__ bool amLast;
    const int wid = threadIdx.x >> 6;
    if ((threadIdx.x & 63) == 0) {
        sc[wid] = count; smh[wid] = minh; sMh[wid] = maxh;
        smw[wid] = minw; sMw[wid] = maxw;
    }
    __syncthreads();

    if (threadIdx.x == 0) {
        int c = 0, mh = INT_MAX, Mh = -1, mw = INT_MAX, Mw = -1;
        #pragma unroll
        for (int i = 0; i < 4; ++i) {
            c += sc[i];
            mh = min(mh, smh[i]); Mh = max(Mh, sMh[i]);
            mw = min(mw, smw[i]); Mw = max(Mw, sMw[i]);
        }
        part[0 * NBLOCKS + blk] = c;
        part[1 * NBLOCKS + blk] = mh;
        part[2 * NBLOCKS + blk] = Mh;
        part[3 * NBLOCKS + blk] = mw;
        part[4 * NBLOCKS + blk] = Mw;
        __threadfence();   // release: partials visible device-wide (cross-XCD)
        const unsigned old = atomicAdd((unsigned*)ws, 1u);  // device-scope
        amLast = (old == NBLOCKS - 1);
    }
    __syncthreads();
    if (!amLast) return;

    __threadfence();       // acquire side in the last-arriving block

    // Final reduce inside the last block: thread b < BATCH folds batch b's
    // 16 partials; empty-mask fallback = full-image bbox (argmax-on-false).
    int diff = 0;
    if (threadIdx.x < BATCH) {
        const int b = threadIdx.x;
        int c = 0, mh = INT_MAX, Mh = -1, mw = INT_MAX, Mw = -1;
        #pragma unroll
        for (int s = 0; s < BLOCKS_PER_BATCH; ++s) {
            const int k = b * BLOCKS_PER_BATCH + s;
            c  += part[0 * NBLOCKS + k];
            mh  = min(mh, part[1 * NBLOCKS + k]);
            Mh  = max(Mh, part[2 * NBLOCKS + k]);
            mw  = min(mw, part[3 * NBLOCKS + k]);
            Mw  = max(Mw, part[4 * NBLOCKS + k]);
        }
        const int area = (Mh < 0) ? (IMG_H * IMG_W)
                                  : (Mh - mh + 1) * (Mw - mw + 1);
        diff = area - c;   // exact: pred_bin is always a subset of its bbox
    }

    #pragma unroll
    for (int off = 32; off; off >>= 1)
        diff += __shfl_down(diff, off);

    __shared__ int s2[4];
    if ((threadIdx.x & 63) == 0) s2[threadIdx.x >> 6] = diff;
    __syncthreads();

    if (threadIdx.x == 0) {
        // Total can reach ~2^24; go through double so the /128 (exact pow2)
        // happens before the single rounding to f32.  (s2[2],s2[3] are 0.)
        const double total = (double)s2[0] + (double)s2[1]
                           + (double)s2[2] + (double)s2[3];
        out[0] = (float)(total / (double)BATCH);   // WEIGHT == 1.0
    }
}

extern "C" void kernel_launch(void* const* d_in, const int* in_sizes, int n_in,
                              void* d_out, int out_size, void* d_ws, size_t ws_size,
                              hipStream_t stream) {
    const float* pred = (const float*)d_in[0];
    int* ws = (int*)d_ws;          // uses 64 + 5*2048 ints ≈ 41 KiB
    float* out = (float*)d_out;

    // Zero the arrival counter (ws is poisoned 0xAA before every timed call).
    // hipMemsetAsync on the capture stream is graph-capture-legal.
    hipMemsetAsync(d_ws, 0, 64 * sizeof(int), stream);
    rect_fused_kernel<<<NBLOCKS, NTHREADS, 0, stream>>>(pred, ws, out);
}

// Round 7
// 190.635 us; speedup vs baseline: 1.2869x; 1.2869x over previous
//
#include <hip/hip_runtime.h>
#include <climits>

#define BATCH 128
#define IMG_H 512
#define IMG_W 512
#define BLOCKS_PER_BATCH 16
#define NTHREADS 256
#define ELEMS_PER_BLOCK (IMG_H * IMG_W / BLOCKS_PER_BATCH)   // 16384
#define VEC_PER_BLOCK   (ELEMS_PER_BLOCK / 4)                // 4096
#define NBLOCKS         (BATCH * BLOCKS_PER_BATCH)           // 2048

typedef float f32x4 __attribute__((ext_vector_type(4)));

// Kernel 1: streaming pass. Each block covers a contiguous 16384-element slice
// (32 full rows) of one batch image. Computes partial {count, minh, maxh,
// minw, maxw} and writes them to ws (no atomics -> no init kernel needed).
// PLAIN vector loads (nontemporal reverted: round-6 evidence says cache
// bypass + fence traffic, not BW, was limiting; nt is the untested suspect).
__global__ __launch_bounds__(NTHREADS)
void rect_partial_kernel(const float* __restrict__ in, int* __restrict__ ws) {
    const int blk   = blockIdx.x;
    const int batch = blk / BLOCKS_PER_BATCH;
    const int sub   = blk % BLOCKS_PER_BATCH;
    const int elemBase = sub * ELEMS_PER_BLOCK;

    const f32x4* base =
        (const f32x4*)(in + (size_t)batch * IMG_H * IMG_W + elemBase);

    int count = 0;
    int minh = INT_MAX, maxh = -1;
    int minw = INT_MAX, maxw = -1;

    // 16 iterations; unroll 8 so 8 independent dwordx4 loads are in flight
    // before the first dependent VALU op.
    #pragma unroll 8
    for (int i = threadIdx.x; i < VEC_PER_BLOCK; i += NTHREADS) {
        const f32x4 v = base[i];
        const int idx = elemBase + i * 4;      // element index within image
        const int h  = idx >> 9;               // /512
        const int w0 = idx & 511;              // %512 (float4 never crosses a row)

        const bool b0 = v.x > 0.5f;
        const bool b1 = v.y > 0.5f;
        const bool b2 = v.z > 0.5f;
        const bool b3 = v.w > 0.5f;
        count += (int)b0 + (int)b1 + (int)b2 + (int)b3;

        if (b0 | b1 | b2 | b3) {
            minh = min(minh, h);
            maxh = max(maxh, h);
            const int fw = b0 ? 0 : (b1 ? 1 : (b2 ? 2 : 3));
            const int lw = b3 ? 3 : (b2 ? 2 : (b1 ? 1 : 0));
            minw = min(minw, w0 + fw);
            maxw = max(maxw, w0 + lw);
        }
    }

    // wave (64-lane) butterfly reduction
    #pragma unroll
    for (int off = 32; off; off >>= 1) {
        count += __shfl_down(count, off);
        minh = min(minh, __shfl_down(minh, off));
        maxh = max(maxh, __shfl_down(maxh, off));
        minw = min(minw, __shfl_down(minw, off));
        maxw = max(maxw, __shfl_down(maxw, off));
    }

    __shared__ int sc[4], smh[4], sMh[4], smw[4], sMw[4];
    const int wid = threadIdx.x >> 6;
    if ((threadIdx.x & 63) == 0) {
        sc[wid] = count; smh[wid] = minh; sMh[wid] = maxh;
        smw[wid] = minw; sMw[wid] = maxw;
    }
    __syncthreads();

    if (threadIdx.x == 0) {
        int c = 0, mh = INT_MAX, Mh = -1, mw = INT_MAX, Mw = -1;
        #pragma unroll
        for (int i = 0; i < 4; ++i) {
            c += sc[i];
            mh = min(mh, smh[i]); Mh = max(Mh, sMh[i]);
            mw = min(mw, smw[i]); Mw = max(Mw, sMw[i]);
        }
        ws[0 * NBLOCKS + blk] = c;
        ws[1 * NBLOCKS + blk] = mh;
        ws[2 * NBLOCKS + blk] = Mh;
        ws[3 * NBLOCKS + blk] = mw;
        ws[4 * NBLOCKS + blk] = Mw;
    }
}

// Kernel 2: fold 16 partials per batch, compute (bbox_area - count) with the
// empty-mask fallback (argmax-on-all-false => full-image bbox), sum across
// batches in exact integer arithmetic, emit WEIGHT * total / B as f32.
__global__ __launch_bounds__(BATCH)
void rect_final_kernel(const int* __restrict__ ws, float* __restrict__ out) {
    const int b = threadIdx.x;   // one thread per batch, 128 threads = 2 waves

    int c = 0, mh = INT_MAX, Mh = -1, mw = INT_MAX, Mw = -1;
    #pragma unroll
    for (int s = 0; s < BLOCKS_PER_BATCH; ++s) {
        const int blk = b * BLOCKS_PER_BATCH + s;
        c  += ws[0 * NBLOCKS + blk];
        mh  = min(mh, ws[1 * NBLOCKS + blk]);
        Mh  = max(Mh, ws[2 * NBLOCKS + blk]);
        mw  = min(mw, ws[3 * NBLOCKS + blk]);
        Mw  = max(Mw, ws[4 * NBLOCKS + blk]);
    }

    const int area = (Mh < 0) ? (IMG_H * IMG_W)
                              : (Mh - mh + 1) * (Mw - mw + 1);
    int diff = area - c;   // exact: pred_bin is always a subset of its bbox

    #pragma unroll
    for (int off = 32; off; off >>= 1)
        diff += __shfl_down(diff, off);

    __shared__ int s2[2];
    if ((threadIdx.x & 63) == 0) s2[threadIdx.x >> 6] = diff;
    __syncthreads();

    if (threadIdx.x == 0) {
        // Total can reach ~2^24; go through double so the /128 (exact pow2)
        // happens before the single rounding to f32.
        const double total = (double)s2[0] + (double)s2[1];
        out[0] = (float)(total / (double)BATCH);   // WEIGHT == 1.0
    }
}

extern "C" void kernel_launch(void* const* d_in, const int* in_sizes, int n_in,
                              void* d_out, int out_size, void* d_ws, size_t ws_size,
                              hipStream_t stream) {
    const float* pred = (const float*)d_in[0];
    int* ws = (int*)d_ws;          // needs 5 * 2048 * 4 B = 40 KiB
    float* out = (float*)d_out;

    rect_partial_kernel<<<NBLOCKS, NTHREADS, 0, stream>>>(pred, ws);
    rect_final_kernel<<<1, BATCH, 0, stream>>>(ws, out);
}

// Round 8
// 178.314 us; speedup vs baseline: 1.3758x; 1.0691x over previous
//
#include <hip/hip_runtime.h>
#include <climits>

#define BATCH 128
#define IMG_H 512
#define IMG_W 512
#define BLOCKS_PER_BATCH 16
#define NTHREADS 256
#define ELEMS_PER_BLOCK (IMG_H * IMG_W / BLOCKS_PER_BATCH)   // 16384
#define VEC_PER_BLOCK   (ELEMS_PER_BLOCK / 4)                // 4096
#define NBLOCKS         (BATCH * BLOCKS_PER_BATCH)           // 2048

// Native vector type: __builtin_nontemporal_load requires a true clang
// vector (HIP's float4 is a class and is rejected).
typedef float f32x4 __attribute__((ext_vector_type(4)));

// Kernel 1: streaming pass. Each block covers a contiguous 16384-element slice
// (32 full rows) of one batch image. Computes partial {count, minh, maxh,
// minw, maxw} and writes them to ws (no atomics -> no init kernel needed).
// EXACT round-5 configuration (best measured: 178.7 µs total): nt loads +
// unroll 4. Round-7's plain-load + unroll-8 variant measured +11.9 µs.
__global__ __launch_bounds__(NTHREADS)
void rect_partial_kernel(const float* __restrict__ in, int* __restrict__ ws) {
    const int blk   = blockIdx.x;
    const int batch = blk / BLOCKS_PER_BATCH;
    const int sub   = blk % BLOCKS_PER_BATCH;
    const int elemBase = sub * ELEMS_PER_BLOCK;

    const f32x4* base =
        (const f32x4*)(in + (size_t)batch * IMG_H * IMG_W + elemBase);

    int count = 0;
    int minh = INT_MAX, maxh = -1;
    int minw = INT_MAX, maxw = -1;

    // 16 iterations; unroll 4 so 4 independent dwordx4 loads are in flight
    // before the first dependent VALU op (MLP for the HBM-bound stream).
    #pragma unroll 4
    for (int i = threadIdx.x; i < VEC_PER_BLOCK; i += NTHREADS) {
        f32x4 v = __builtin_nontemporal_load(&base[i]);  // read-once stream
        const int idx = elemBase + i * 4;      // element index within image
        const int h  = idx >> 9;               // /512
        const int w0 = idx & 511;              // %512 (float4 never crosses a row)

        const bool b0 = v.x > 0.5f;
        const bool b1 = v.y > 0.5f;
        const bool b2 = v.z > 0.5f;
        const bool b3 = v.w > 0.5f;
        count += (int)b0 + (int)b1 + (int)b2 + (int)b3;

        if (b0 | b1 | b2 | b3) {
            minh = min(minh, h);
            maxh = max(maxh, h);
            const int fw = b0 ? 0 : (b1 ? 1 : (b2 ? 2 : 3));
            const int lw = b3 ? 3 : (b2 ? 2 : (b1 ? 1 : 0));
            minw = min(minw, w0 + fw);
            maxw = max(maxw, w0 + lw);
        }
    }

    // wave (64-lane) butterfly reduction
    #pragma unroll
    for (int off = 32; off; off >>= 1) {
        count += __shfl_down(count, off);
        minh = min(minh, __shfl_down(minh, off));
        maxh = max(maxh, __shfl_down(maxh, off));
        minw = min(minw, __shfl_down(minw, off));
        maxw = max(maxw, __shfl_down(maxw, off));
    }

    __shared__ int sc[4], smh[4], sMh[4], smw[4], sMw[4];
    const int wid = threadIdx.x >> 6;
    if ((threadIdx.x & 63) == 0) {
        sc[wid] = count; smh[wid] = minh; sMh[wid] = maxh;
        smw[wid] = minw; sMw[wid] = maxw;
    }
    __syncthreads();

    if (threadIdx.x == 0) {
        int c = 0, mh = INT_MAX, Mh = -1, mw = INT_MAX, Mw = -1;
        #pragma unroll
        for (int i = 0; i < 4; ++i) {
            c += sc[i];
            mh = min(mh, smh[i]); Mh = max(Mh, sMh[i]);
            mw = min(mw, smw[i]); Mw = max(Mw, sMw[i]);
        }
        ws[0 * NBLOCKS + blk] = c;
        ws[1 * NBLOCKS + blk] = mh;
        ws[2 * NBLOCKS + blk] = Mh;
        ws[3 * NBLOCKS + blk] = mw;
        ws[4 * NBLOCKS + blk] = Mw;
    }
}

// Kernel 2: fold 16 partials per batch, compute (bbox_area - count) with the
// empty-mask fallback (argmax-on-all-false => full-image bbox), sum across
// batches in exact integer arithmetic, emit WEIGHT * total / B as f32.
__global__ __launch_bounds__(BATCH)
void rect_final_kernel(const int* __restrict__ ws, float* __restrict__ out) {
    const int b = threadIdx.x;   // one thread per batch, 128 threads = 2 waves

    int c = 0, mh = INT_MAX, Mh = -1, mw = INT_MAX, Mw = -1;
    #pragma unroll
    for (int s = 0; s < BLOCKS_PER_BATCH; ++s) {
        const int blk = b * BLOCKS_PER_BATCH + s;
        c  += ws[0 * NBLOCKS + blk];
        mh  = min(mh, ws[1 * NBLOCKS + blk]);
        Mh  = max(Mh, ws[2 * NBLOCKS + blk]);
        mw  = min(mw, ws[3 * NBLOCKS + blk]);
        Mw  = max(Mw, ws[4 * NBLOCKS + blk]);
    }

    const int area = (Mh < 0) ? (IMG_H * IMG_W)
                              : (Mh - mh + 1) * (Mw - mw + 1);
    int diff = area - c;   // exact: pred_bin is always a subset of its bbox

    #pragma unroll
    for (int off = 32; off; off >>= 1)
        diff += __shfl_down(diff, off);

    __shared__ int s2[2];
    if ((threadIdx.x & 63) == 0) s2[threadIdx.x >> 6] = diff;
    __syncthreads();

    if (threadIdx.x == 0) {
        // Total can reach ~2^24; go through double so the /128 (exact pow2)
        // happens before the single rounding to f32.
        const double total = (double)s2[0] + (double)s2[1];
        out[0] = (float)(total / (double)BATCH);   // WEIGHT == 1.0
    }
}

extern "C" void kernel_launch(void* const* d_in, const int* in_sizes, int n_in,
                              void* d_out, int out_size, void* d_ws, size_t ws_size,
                              hipStream_t stream) {
    const float* pred = (const float*)d_in[0];
    int* ws = (int*)d_ws;          // needs 5 * 2048 * 4 B = 40 KiB
    float* out = (float*)d_out;

    rect_partial_kernel<<<NBLOCKS, NTHREADS, 0, stream>>>(pred, ws);
    rect_final_kernel<<<1, BATCH, 0, stream>>>(ws, out);
}